// Round 8
// baseline (422.850 us; speedup 1.0000x reference)
//
#include <hip/hip_runtime.h>
#include <stdint.h>

typedef unsigned int u32;
typedef unsigned long long u64;

#define NTOT 21824   // 128*128 + 64*64 + 32*32 + 16*16 + 8*8 = 341*64
#define NBATCH 16
#define TOPN 1000
#define MAXOBJ 100
#define CAP 2048     // refine until candidate count <= CAP
#define CAPC 8192    // candidate buffer capacity per batch
#define CHROWS 64    // rows per scan chunk (must be 64: word-aligned scan)
#define NCHUNK 16    // 15*64 + 40 = 1000

// -------------------------------------------------------------------------
// Stage 1: decode (argmax over 80 classes + score key).  Grid-stride over
// 64-location chunks: 1536 long-lived blocks (~6/CU) instead of 5456
// ephemeral ones (R5 showed 34% achieved occupancy from ramp/drain).
// Quad-per-location: 4 lanes share one location, 64 B contiguous per load.
// -------------------------------------------------------------------------
__global__ __launch_bounds__(256) void decode_kernel(
    const float* __restrict__ cls0, const float* __restrict__ cls1,
    const float* __restrict__ cls2, const float* __restrict__ cls3,
    const float* __restrict__ cls4,
    const float* __restrict__ ctr0, const float* __restrict__ ctr1,
    const float* __restrict__ ctr2, const float* __restrict__ ctr3,
    const float* __restrict__ ctr4,
    u32* __restrict__ keys, int* __restrict__ clsidx)
{
    int tid = threadIdx.x;
    int g = tid >> 2, j = tid & 3;          // location-in-chunk, quad sub
    int b = blockIdx.y;
    for (int bx = blockIdx.x; bx < NTOT / 64; bx += gridDim.x) {
        int loc = bx * 64 + g;              // level-uniform per chunk; no tail
        const float *cp, *tp;
        if (loc < 16384)      { size_t o = (size_t)b*16384 + loc;          cp = cls0 + o*80; tp = ctr0 + o; }
        else if (loc < 20480) { size_t o = (size_t)b*4096  + (loc-16384);  cp = cls1 + o*80; tp = ctr1 + o; }
        else if (loc < 21504) { size_t o = (size_t)b*1024  + (loc-20480);  cp = cls2 + o*80; tp = ctr2 + o; }
        else if (loc < 21760) { size_t o = (size_t)b*256   + (loc-21504);  cp = cls3 + o*80; tp = ctr3 + o; }
        else                  { size_t o = (size_t)b*64    + (loc-21760);  cp = cls4 + o*80; tp = ctr4 + o; }

        const float4* c4 = (const float4*)cp;
        float maxv = -1.0f; int arg = 0;
#pragma unroll
        for (int q = 0; q < 5; ++q) {
            float4 v = c4[j + 4*q];
            int ch = 16*q + 4*j;
            if (v.x > maxv) { maxv = v.x; arg = ch;     }
            if (v.y > maxv) { maxv = v.y; arg = ch + 1; }
            if (v.z > maxv) { maxv = v.z; arg = ch + 2; }
            if (v.w > maxv) { maxv = v.w; arg = ch + 3; }
        }
        // quad reduction, exact first-max tie-break (lowest channel wins)
#pragma unroll
        for (int d = 1; d <= 2; d <<= 1) {
            float ov = __shfl_xor(maxv, d);
            int   oa = __shfl_xor(arg, d);
            if (ov > maxv || (ov == maxv && oa < arg)) { maxv = ov; arg = oa; }
        }
        if (j == 0) {
            float score = sqrtf(maxv * (*tp));   // correctly-rounded fp32 sqrt
            u32 key = (score > 0.05f) ? (__float_as_uint(score) | 0x80000000u) : 0u;
            size_t o = (size_t)b * NTOT + loc;
            keys[o] = key;
            clsidx[o] = arg;
        }
    }
}

// -------------------------------------------------------------------------
// IoU bit computation for one 64-row chunk into LDS (replaces the old
// global sup matrix).  Words w < row>>6 are all-zero (col<=row) -- skipped.
// Exact same fp32 IoU ops as before (incl. the correctly-rounded divide).
// -------------------------------------------------------------------------
__device__ __forceinline__ void compute_chunk(
    int c, int idx, int nw, int lane,
    const float4* sbox, const float* sarea, u64* matc)
{
    int r0 = c * CHROWS;
    int rows = (TOPN - r0 < CHROWS) ? (TOPN - r0) : CHROWS;
    for (int r = idx; r < rows; r += nw) {
        int row = r0 + r;
        float4 bi = sbox[row];
        float areai = sarea[row];
        int wstart = row >> 6;              // == c for all rows in chunk
        if (lane < wstart) matc[r * 16 + lane] = 0;
        for (int w = wstart; w < 16; ++w) {
            int col = w * 64 + lane;
            bool bit = false;
            if (col < TOPN && col > row) {
                float4 bj = sbox[col];
                float areaj = sarea[col];
                float tlx = fmaxf(bi.x, bj.x), tly = fmaxf(bi.y, bj.y);
                float brx = fminf(bi.z, bj.z), bry = fminf(bi.w, bj.w);
                float ow = fmaxf(brx - tlx, 0.f), oh = fmaxf(bry - tly, 0.f);
                float inter = ow * oh;
                float uni = fmaxf(areai + areaj - inter, 0.0001f);
                bit = (inter / uni >= 0.6f);
            }
            u64 m = __ballot(bit);
            if (lane == w) matc[r * 16 + w] = m;
        }
    }
}

// -------------------------------------------------------------------------
// Stage 2: EVERYTHING after decode, one block per batch.
// pivot (radix refine) -> gather -> rank (readlane) into LDS ->
// on-the-fly IoU chunks overlapped with the serial greedy scan -> output.
// LDS: shbuf 32 KB (hist, then sbox/sarea/sscore/scls) + mat 16 KB.
// -------------------------------------------------------------------------
__global__ __launch_bounds__(1024) void mega_kernel(
    const u32* __restrict__ keys, const int* __restrict__ clsidx,
    const float* __restrict__ reg0, const float* __restrict__ reg1,
    const float* __restrict__ reg2, const float* __restrict__ reg3,
    const float* __restrict__ reg4,
    u64* __restrict__ cb, u64* __restrict__ cb2,
    float* __restrict__ out)
{
    __shared__ __align__(16) u64 shbuf[4096];   // 32 KB
    __shared__ u64 mat[2][CHROWS * 16];         // 16 KB
    __shared__ u32 s_wtot[16];
    __shared__ int s_tf;
    __shared__ u32 s_C, s_above, s_cnt;
    __shared__ u64 removed_sh[16];
    __shared__ u32 wpref[17];

    u32* h4flat = (u32*)shbuf;                  // [4][2048] during pivot
    int b = blockIdx.x, tid = threadIdx.x;
    int lane = tid & 63, wave = tid >> 6, hsub = wave & 3;
    const u32* kb = keys + (size_t)b * NTOT;
    u64* cbb = cb + (size_t)b * CAPC;
    u64* c2b = cb2 + (size_t)b * CAPC;

    // ---- phase A: 11-bit histogram ----
    for (int i = tid; i < 8192; i += 1024) h4flat[i] = 0;
    if (tid == 0) { s_tf = -1; s_cnt = 0; }
    __syncthreads();
    for (int i = tid; i < NTOT; i += 1024) {
        u32 k = kb[i];
        if (k) atomicAdd(&h4flat[hsub * 2048 + (k >> 21)], 1u);
    }
    __syncthreads();
    u32 h0 = h4flat[2*tid] + h4flat[2048 + 2*tid] + h4flat[4096 + 2*tid] + h4flat[6144 + 2*tid];
    u32 h1 = h4flat[2*tid+1] + h4flat[2048 + 2*tid+1] + h4flat[4096 + 2*tid+1] + h4flat[6144 + 2*tid+1];
    u32 x = h0 + h1;
#pragma unroll
    for (int off = 1; off < 64; off <<= 1) {
        u32 y = __shfl_down(x, off);
        if (lane + off < 64) x += y;
    }
    if (lane == 0) s_wtot[wave] = x;
    __syncthreads();
    u32 wsuf = 0, tot = 0;
    for (int w2 = 0; w2 < 16; ++w2) { u32 v = s_wtot[w2]; tot += v; if (w2 > wave) wsuf += v; }
    u32 suf0 = x + wsuf, suf1 = suf0 - h0;
    u32 target = (tot < TOPN) ? tot : TOPN;
    if (target > 0) {
        if (suf0 >= target) atomicMax(&s_tf, 2 * tid);
        if (suf1 >= target) atomicMax(&s_tf, 2 * tid + 1);
    }
    __syncthreads();
    int t0 = s_tf;
    if (target > 0) {
        if (2 * tid == t0)     { s_C = suf0; s_above = suf0 - h0; }
        if (2 * tid + 1 == t0) { s_C = suf1; s_above = suf1 - h1; }
    }
    __syncthreads();
    u32 C0 = (target > 0) ? s_C : 0;
    u32 above0 = (target > 0) ? s_above : 0;
    bool useCand = (C0 <= CAPC);

    // ---- phase B: gather bins >= t0 into cbb ----
    for (int base = 0; base < NTOT; base += 1024) {
        int i = base + tid;
        u32 k = (i < NTOT) ? kb[i] : 0u;
        bool pass = (target > 0) && k && ((int)(k >> 21) >= t0);
        u64 mask = __ballot(pass);
        u32 wcnt = (u32)__popcll(mask);
        u32 wbase = 0;
        if (lane == 0 && wcnt) wbase = atomicAdd(&s_cnt, wcnt);
        wbase = __shfl(wbase, 0);
        if (pass) {
            u32 pos = wbase + (u32)__popcll(mask & ((1ull << lane) - 1ull));
            if (pos < CAPC) cbb[pos] = ((u64)k << 32) | (u32)(~i);
        }
    }
    __syncthreads();
    if (tid == 0) s_cnt = 0;

    // ---- phase C: level-2 refine ----
    bool need2 = (target > 0 && C0 > CAP);
    int t1 = 0; u32 C1 = 0, above1 = 0;
    for (int i = tid; i < 8192; i += 1024) h4flat[i] = 0;
    if (tid == 0) s_tf = -1;
    __syncthreads();
    if (need2) {
        if (useCand) {
            for (u32 i = tid; i < C0; i += 1024) {
                u32 k = (u32)(cbb[i] >> 32);
                if ((int)(k >> 21) == t0) atomicAdd(&h4flat[hsub * 2048 + ((k >> 10) & 2047)], 1u);
            }
        } else {
            for (int i = tid; i < NTOT; i += 1024) {
                u32 k = kb[i];
                if (k && (int)(k >> 21) == t0) atomicAdd(&h4flat[hsub * 2048 + ((k >> 10) & 2047)], 1u);
            }
        }
    }
    __syncthreads();
    {
        u32 g0 = h4flat[2*tid] + h4flat[2048 + 2*tid] + h4flat[4096 + 2*tid] + h4flat[6144 + 2*tid];
        u32 g1 = h4flat[2*tid+1] + h4flat[2048 + 2*tid+1] + h4flat[4096 + 2*tid+1] + h4flat[6144 + 2*tid+1];
        u32 x2 = g0 + g1;
#pragma unroll
        for (int off = 1; off < 64; off <<= 1) {
            u32 y = __shfl_down(x2, off);
            if (lane + off < 64) x2 += y;
        }
        if (lane == 0) s_wtot[wave] = x2;
        __syncthreads();
        u32 ws2 = 0;
        for (int w2 = wave + 1; w2 < 16; ++w2) ws2 += s_wtot[w2];
        u32 sa0 = x2 + ws2, sa1 = sa0 - g0;
        u32 need2c = target - above0;
        if (need2) {
            if (sa0 >= need2c) atomicMax(&s_tf, 2 * tid);
            if (sa1 >= need2c) atomicMax(&s_tf, 2 * tid + 1);
        }
        __syncthreads();
        t1 = s_tf;
        if (need2) {
            if (2 * tid == t1)     { s_C = above0 + sa0; s_above = above0 + sa0 - g0; }
            if (2 * tid + 1 == t1) { s_C = above0 + sa1; s_above = above0 + sa1 - g1; }
        }
        __syncthreads();
        if (need2) { C1 = s_C; above1 = s_above; }
    }

    // ---- phase D: level-3 refine ----
    bool need3 = (need2 && C1 > CAP);
    int t2 = 0;
    __syncthreads();
    for (int i = tid; i < 8192; i += 1024) h4flat[i] = 0;
    if (tid == 0) s_tf = -1;
    __syncthreads();
    if (need3) {
        if (useCand) {
            for (u32 i = tid; i < C0; i += 1024) {
                u32 k = (u32)(cbb[i] >> 32);
                if ((int)(k >> 21) == t0 && (int)((k >> 10) & 2047) == t1)
                    atomicAdd(&h4flat[hsub * 2048 + (k & 1023)], 1u);
            }
        } else {
            for (int i = tid; i < NTOT; i += 1024) {
                u32 k = kb[i];
                if (k && (int)(k >> 21) == t0 && (int)((k >> 10) & 2047) == t1)
                    atomicAdd(&h4flat[hsub * 2048 + (k & 1023)], 1u);
            }
        }
    }
    __syncthreads();
    {
        u32 g0 = h4flat[2*tid] + h4flat[2048 + 2*tid] + h4flat[4096 + 2*tid] + h4flat[6144 + 2*tid];
        u32 g1 = h4flat[2*tid+1] + h4flat[2048 + 2*tid+1] + h4flat[4096 + 2*tid+1] + h4flat[6144 + 2*tid+1];
        u32 x3 = g0 + g1;
#pragma unroll
        for (int off = 1; off < 64; off <<= 1) {
            u32 y = __shfl_down(x3, off);
            if (lane + off < 64) x3 += y;
        }
        if (lane == 0) s_wtot[wave] = x3;
        __syncthreads();
        u32 ws3 = 0;
        for (int w2 = wave + 1; w2 < 16; ++w2) ws3 += s_wtot[w2];
        u32 sb0 = x3 + ws3, sb1 = sb0 - g0;
        if (need3) {
            u32 need3c = target - above1;
            if (sb0 >= need3c) atomicMax(&s_tf, 2 * tid);
            if (sb1 >= need3c) atomicMax(&s_tf, 2 * tid + 1);
        }
        __syncthreads();
        t2 = s_tf;
    }

    // ---- phase E: compact >= P into cb2 (global) ----
    u32 P;
    if (target == 0) P = 0xFFFFFFFFu;
    else if (!need2) P = (u32)t0 << 21;
    else if (!need3) P = ((u32)t0 << 21) | ((u32)t1 << 10);
    else             P = ((u32)t0 << 21) | ((u32)t1 << 10) | (u32)t2;

    __syncthreads();
    if (useCand) {
        u32 Cr = (C0 + 1023u) & ~1023u;
        for (u32 base = 0; base < Cr; base += 1024) {
            u32 i = base + tid;
            u64 e = 0; bool pass = false;
            if (i < C0 && target > 0) { e = cbb[i]; pass = ((u32)(e >> 32) >= P); }
            u64 mask = __ballot(pass);
            u32 wcnt = (u32)__popcll(mask);
            u32 wbase = 0;
            if (lane == 0 && wcnt) wbase = atomicAdd(&s_cnt, wcnt);
            wbase = __shfl(wbase, 0);
            if (pass) {
                u32 pos = wbase + (u32)__popcll(mask & ((1ull << lane) - 1ull));
                if (pos < CAPC) c2b[pos] = e;
            }
        }
    } else {
        for (int base = 0; base < NTOT; base += 1024) {
            int i = base + tid;
            u32 k = (i < NTOT) ? kb[i] : 0u;
            bool pass = (target > 0) && k && (k >= P);
            u64 mask = __ballot(pass);
            u32 wcnt = (u32)__popcll(mask);
            u32 wbase = 0;
            if (lane == 0 && wcnt) wbase = atomicAdd(&s_cnt, wcnt);
            wbase = __shfl(wbase, 0);
            if (pass) {
                u32 pos = wbase + (u32)__popcll(mask & ((1ull << lane) - 1ull));
                if (pos < CAPC) c2b[pos] = ((u64)k << 32) | (u32)(~i);
            }
        }
    }
    __syncthreads();
    u32 M = s_cnt; if (M > CAPC) M = CAPC;

    // ---- re-purpose shbuf: result arrays in LDS (hist is dead) ----
    float4* sbox  = (float4*)shbuf;                     // 16000 B
    float*  sarea = (float*)((char*)shbuf + 16000);     //  4000 B
    float*  sscore= (float*)((char*)shbuf + 20000);     //  4000 B
    float*  scls  = (float*)((char*)shbuf + 24000);     //  4000 B
    __syncthreads();
    for (int i = tid; i < TOPN; i += 1024) {
        sscore[i] = -1.0f; scls[i] = -1.0f;
        sbox[i] = make_float4(0.f, 0.f, 0.f, 0.f);
    }
    __syncthreads();

    // ---- rank-by-count (coalesced chunk load + readlane broadcast) ----
    u32 Mr = (M + 63u) & ~63u;
    for (u32 base = wave * 64; base < M; base += 16 * 64) {   // uniform per wave
        u32 i0 = base + lane;
        bool val = (i0 < M);
        u64 e = val ? c2b[i0] : ~0ull;
        u32 r = 0;
        for (u32 c0 = 0; c0 < Mr; c0 += 64) {
            u32 jj = c0 + lane;
            u64 v = (jj < M) ? c2b[jj] : 0ull;   // 0 never > any candidate
            u32 vlo = (u32)v, vhi = (u32)(v >> 32);
#pragma unroll
            for (int s = 0; s < 64; ++s) {
                u32 lo = (u32)__builtin_amdgcn_readlane((int)vlo, s);
                u32 hi = (u32)__builtin_amdgcn_readlane((int)vhi, s);
                u64 vj = ((u64)hi << 32) | lo;
                r += (vj > e) ? 1u : 0u;
            }
        }
        if (val && r < target) {
            u32 k = (u32)(e >> 32);
            u32 loc = ~(u32)e;
            const float* rp; float st; u32 li; int wsh;
            if (loc < 16384u)      { li = loc;          wsh = 7; st = 8.f;   rp = reg0 + ((size_t)b*16384 + li)*4; }
            else if (loc < 20480u) { li = loc - 16384u; wsh = 6; st = 16.f;  rp = reg1 + ((size_t)b*4096  + li)*4; }
            else if (loc < 21504u) { li = loc - 20480u; wsh = 5; st = 32.f;  rp = reg2 + ((size_t)b*1024  + li)*4; }
            else if (loc < 21760u) { li = loc - 21504u; wsh = 4; st = 64.f;  rp = reg3 + ((size_t)b*256   + li)*4; }
            else                   { li = loc - 21760u; wsh = 3; st = 128.f; rp = reg4 + ((size_t)b*64    + li)*4; }
            u32 wx = li & ((1u << wsh) - 1u);
            u32 hy = li >> wsh;
            float px = ((float)wx + 0.5f) * st;
            float py = ((float)hy + 0.5f) * st;
            float4 rg = *(const float4*)rp;
            float4 bx;
            bx.x = truncf(px - rg.x); bx.y = truncf(py - rg.y);
            bx.z = truncf(px + rg.z); bx.w = truncf(py + rg.w);
            sscore[r] = __uint_as_float(k & 0x7FFFFFFFu);
            scls[r] = (float)clsidx[(size_t)b * NTOT + loc];
            sbox[r] = bx;
        }
    }
    __syncthreads();

    // ---- areas (exact reference clip) ----
    for (int i = tid; i < TOPN; i += 1024) {
        float4 bb = sbox[i];
        sarea[i] = fmaxf((bb.z - bb.x) * (bb.w - bb.y), 0.0001f);
    }
    __syncthreads();

    // ---- seed removed with ~valid ----
    u64 my = 0;
    if (wave == 0) {
#pragma unroll
        for (int w2 = 0; w2 < 16; ++w2) {
            int i = w2 * 64 + lane;
            bool v = (i < TOPN) ? (sscore[i] > 0.05f) : false;
            u64 m = __ballot(v);
            if (lane == w2) my = ~m;
        }
    }
    // chunk 0 computed by all 16 waves
    compute_chunk(0, wave, 16, lane, sbox, sarea, mat[0]);
    __syncthreads();

    // ---- overlapped IoU-compute + serial greedy scan ----
    for (int chunk = 0; chunk < NCHUNK; ++chunk) {
        if (wave > 0 && chunk + 1 < NCHUNK)
            compute_chunk(chunk + 1, wave - 1, 15, lane, sbox, sarea, mat[(chunk + 1) & 1]);
        if (wave == 0) {
            int r0 = chunk * CHROWS;
            int rows = (chunk == NCHUNK - 1) ? (TOPN - r0) : CHROWS;  // 64 or 40
            int lw = lane & 15;
            const u64* R = mat[chunk & 1];
            u64 cur = __shfl(my, chunk);
            int ngrp = rows >> 3;                   // 8 or 5
            u64 cme[8], cww[8];
#pragma unroll
            for (int g2 = 0; g2 < 8; ++g2) { cme[g2] = R[g2*16 + lw]; cww[g2] = R[g2*16 + chunk]; }
            for (int grp = 0; grp < ngrp; ++grp) {
                u64 nme[8] = {0,0,0,0,0,0,0,0}, nww[8] = {0,0,0,0,0,0,0,0};
                if (grp + 1 < ngrp) {
                    const u64* Rn = R + (grp + 1) * 128;
#pragma unroll
                    for (int g2 = 0; g2 < 8; ++g2) { nme[g2] = Rn[g2*16 + lw]; nww[g2] = Rn[g2*16 + chunk]; }
                }
#pragma unroll
                for (int g2 = 0; g2 < 8; ++g2) {
                    int u = grp * 8 + g2;
                    u64 bit = (cur >> u) & 1ull;
                    u64 act = bit - 1ull;           // active -> all-ones
                    cur |= cww[g2] & act;
                    my  |= cme[g2] & act;
                }
#pragma unroll
                for (int g2 = 0; g2 < 8; ++g2) { cme[g2] = nme[g2]; cww[g2] = nww[g2]; }
            }
        }
        __syncthreads();
    }
    if (wave == 0) {
        if (lane < 16) removed_sh[lane] = my;
        u32 pc = (lane < 16) ? (u32)__popcll(~my) : 0u;
#pragma unroll
        for (int off = 1; off < 16; off <<= 1) {
            u32 y = __shfl_up(pc, off);
            if (lane >= off) pc += y;
        }
        if (lane < 16) wpref[lane + 1] = pc;
        if (lane == 0) wpref[0] = 0;
    }
    __syncthreads();

    // ---- output ----
    float* out_s = out;
    float* out_c = out + NBATCH * MAXOBJ;
    float* out_b = out + 2 * NBATCH * MAXOBJ;
    if (tid < MAXOBJ)     { out_s[b * MAXOBJ + tid] = -1.f; out_c[b * MAXOBJ + tid] = -1.f; }
    if (tid < MAXOBJ * 4) out_b[b * MAXOBJ * 4 + tid] = 0.f;
    __syncthreads();
    if (tid < TOPN) {
        u64 kw = ~removed_sh[tid >> 6];
        if ((kw >> (tid & 63)) & 1ull) {
            int rank = (int)wpref[tid >> 6] + (int)__popcll(kw & ((1ull << (tid & 63)) - 1ull));
            if (rank < MAXOBJ) {
                out_s[b * MAXOBJ + rank] = sscore[tid];
                out_c[b * MAXOBJ + rank] = scls[tid];
                ((float4*)out_b)[b * MAXOBJ + rank] = sbox[tid];
            }
        }
    }
}

// -------------------------------------------------------------------------
// Workspace layout (bytes), total 4,890,624:
//   keys    u32 [16][21824]   @ 0          (1,396,736)
//   clsidx  i32 [16][21824]   @ 1,396,736  (1,396,736)
//   cb      u64 [16][8192]    @ 2,793,472  (1,048,576)
//   cb2     u64 [16][8192]    @ 3,842,048  (1,048,576)
// -------------------------------------------------------------------------
extern "C" void kernel_launch(void* const* d_in, const int* in_sizes, int n_in,
                              void* d_out, int out_size, void* d_ws, size_t ws_size,
                              hipStream_t stream) {
    (void)in_sizes; (void)n_in; (void)out_size; (void)ws_size;
    const float* cls[5]; const float* reg[5]; const float* ctr[5];
    for (int l = 0; l < 5; ++l) {
        cls[l] = (const float*)d_in[4 * l + 0];
        reg[l] = (const float*)d_in[4 * l + 1];
        ctr[l] = (const float*)d_in[4 * l + 2];
    }
    char* w = (char*)d_ws;
    u32* keys   = (u32*)(w + 0);
    int* clsidx = (int*)(w + 1396736);
    u64* cb     = (u64*)(w + 2793472);
    u64* cb2    = (u64*)(w + 3842048);

    decode_kernel<<<dim3(96, NBATCH), 256, 0, stream>>>(
        cls[0], cls[1], cls[2], cls[3], cls[4],
        ctr[0], ctr[1], ctr[2], ctr[3], ctr[4],
        keys, clsidx);
    mega_kernel<<<NBATCH, 1024, 0, stream>>>(
        keys, clsidx,
        reg[0], reg[1], reg[2], reg[3], reg[4],
        cb, cb2, (float*)d_out);
}

// Round 9
// 283.858 us; speedup vs baseline: 1.4897x; 1.4897x over previous
//
#include <hip/hip_runtime.h>
#include <stdint.h>

typedef unsigned int u32;
typedef unsigned long long u64;

#define NTOT 21824   // 128*128 + 64*64 + 32*32 + 16*16 + 8*8
#define NBATCH 16
#define TOPN 1000
#define MAXOBJ 100
#define CAP 2048     // refine until candidate count <= CAP
#define CAPC 8192    // candidate buffer capacity per batch

// -------------------------------------------------------------------------
// Stage 1: decode (argmax over 80 classes + score key).  Pure streaming.
// Quad-per-location (4 lanes/location, 64 B contiguous per load) and TWO
// locations per thread: 11 independent loads in flight (R5 showed decode
// latency-bound at ~2.3 TB/s effective with only 6).
// -------------------------------------------------------------------------
__global__ __launch_bounds__(256) void decode_kernel(
    const float* __restrict__ cls0, const float* __restrict__ cls1,
    const float* __restrict__ cls2, const float* __restrict__ cls3,
    const float* __restrict__ cls4,
    const float* __restrict__ ctr0, const float* __restrict__ ctr1,
    const float* __restrict__ ctr2, const float* __restrict__ ctr3,
    const float* __restrict__ ctr4,
    u32* __restrict__ keys, int* __restrict__ clsidx)
{
    int tid = threadIdx.x;
    int g = tid >> 2, j = tid & 3;          // location-in-half, quad sub
    int b = blockIdx.y;
    int loc0 = blockIdx.x * 128 + g;        // first location
    int loc1 = loc0 + 64;                   // second location
    bool vA = (loc0 < NTOT), vB = (loc1 < NTOT);
    int locA = vA ? loc0 : 0;
    int locB = vB ? loc1 : 0;

    const float *cpa, *tpa, *cpb, *tpb;
    {
        int loc = locA;
        if (loc < 16384)      { size_t o = (size_t)b*16384 + loc;          cpa = cls0 + o*80; tpa = ctr0 + o; }
        else if (loc < 20480) { size_t o = (size_t)b*4096  + (loc-16384);  cpa = cls1 + o*80; tpa = ctr1 + o; }
        else if (loc < 21504) { size_t o = (size_t)b*1024  + (loc-20480);  cpa = cls2 + o*80; tpa = ctr2 + o; }
        else if (loc < 21760) { size_t o = (size_t)b*256   + (loc-21504);  cpa = cls3 + o*80; tpa = ctr3 + o; }
        else                  { size_t o = (size_t)b*64    + (loc-21760);  cpa = cls4 + o*80; tpa = ctr4 + o; }
    }
    {
        int loc = locB;
        if (loc < 16384)      { size_t o = (size_t)b*16384 + loc;          cpb = cls0 + o*80; tpb = ctr0 + o; }
        else if (loc < 20480) { size_t o = (size_t)b*4096  + (loc-16384);  cpb = cls1 + o*80; tpb = ctr1 + o; }
        else if (loc < 21504) { size_t o = (size_t)b*1024  + (loc-20480);  cpb = cls2 + o*80; tpb = ctr2 + o; }
        else if (loc < 21760) { size_t o = (size_t)b*256   + (loc-21504);  cpb = cls3 + o*80; tpb = ctr3 + o; }
        else                  { size_t o = (size_t)b*64    + (loc-21760);  cpb = cls4 + o*80; tpb = ctr4 + o; }
    }

    const float4* a4 = (const float4*)cpa;
    const float4* b4 = (const float4*)cpb;
    // issue all 10 cls loads + 2 ctr loads up-front (independent)
    float4 va[5], vb[5];
#pragma unroll
    for (int q = 0; q < 5; ++q) { va[q] = a4[j + 4*q]; vb[q] = b4[j + 4*q]; }
    float ctra = *tpa, ctrb = *tpb;

    float maxA = -1.0f, maxB = -1.0f; int argA = 0, argB = 0;
#pragma unroll
    for (int q = 0; q < 5; ++q) {
        int ch = 16*q + 4*j;
        float4 v = va[q];
        if (v.x > maxA) { maxA = v.x; argA = ch;     }
        if (v.y > maxA) { maxA = v.y; argA = ch + 1; }
        if (v.z > maxA) { maxA = v.z; argA = ch + 2; }
        if (v.w > maxA) { maxA = v.w; argA = ch + 3; }
        float4 u = vb[q];
        if (u.x > maxB) { maxB = u.x; argB = ch;     }
        if (u.y > maxB) { maxB = u.y; argB = ch + 1; }
        if (u.z > maxB) { maxB = u.z; argB = ch + 2; }
        if (u.w > maxB) { maxB = u.w; argB = ch + 3; }
    }
    // quad reductions, exact first-max tie-break (lowest channel wins)
#pragma unroll
    for (int d = 1; d <= 2; d <<= 1) {
        float ovA = __shfl_xor(maxA, d); int oaA = __shfl_xor(argA, d);
        if (ovA > maxA || (ovA == maxA && oaA < argA)) { maxA = ovA; argA = oaA; }
        float ovB = __shfl_xor(maxB, d); int oaB = __shfl_xor(argB, d);
        if (ovB > maxB || (ovB == maxB && oaB < argB)) { maxB = ovB; argB = oaB; }
    }
    if (j == 0) {
        if (vA) {
            float score = sqrtf(maxA * ctra);    // correctly-rounded fp32 sqrt
            u32 key = (score > 0.05f) ? (__float_as_uint(score) | 0x80000000u) : 0u;
            size_t o = (size_t)b * NTOT + loc0;
            keys[o] = key; clsidx[o] = argA;
        }
        if (vB) {
            float score = sqrtf(maxB * ctrb);
            u32 key = (score > 0.05f) ? (__float_as_uint(score) | 0x80000000u) : 0u;
            size_t o = (size_t)b * NTOT + loc1;
            keys[o] = key; clsidx[o] = argB;
        }
    }
}

// -------------------------------------------------------------------------
// Stage 2: pivot + gather + compact, one block per batch (R6-proven).
// -------------------------------------------------------------------------
__global__ __launch_bounds__(1024) void pivot_kernel(
    const u32* __restrict__ keys,
    u64* __restrict__ cb, u64* __restrict__ cand2,
    u32* __restrict__ gcnt, u32* __restrict__ params,
    float* __restrict__ tscore, float* __restrict__ tcls, float4* __restrict__ tbox)
{
    __shared__ u32 h4[4][2048];     // 32 KB
    __shared__ u32 s_wtot[16];
    __shared__ int s_tf;
    __shared__ u32 s_C, s_above, s_cnt;
    int b = blockIdx.x, tid = threadIdx.x;
    int lane = tid & 63, wave = tid >> 6, sub = wave & 3;
    const u32* kb = keys + (size_t)b * NTOT;
    u64* cbb = cb + (size_t)b * CAPC;
    u64* c2b = cand2 + (size_t)b * CAPC;

    for (int i = tid; i < TOPN; i += 1024) {
        size_t o = (size_t)b * TOPN + i;
        tscore[o] = -1.0f; tcls[o] = -1.0f;
        tbox[o] = make_float4(0.f, 0.f, 0.f, 0.f);
    }

    // ---- phase A: 11-bit histogram from keys ----
    for (int i = tid; i < 4 * 2048; i += 1024) ((u32*)h4)[i] = 0;
    if (tid == 0) { s_tf = -1; s_cnt = 0; }
    __syncthreads();
    for (int i = tid; i < NTOT; i += 1024) {
        u32 k = kb[i];
        if (k) atomicAdd(&h4[sub][k >> 21], 1u);
    }
    __syncthreads();
    u32 h0 = h4[0][2*tid] + h4[1][2*tid] + h4[2][2*tid] + h4[3][2*tid];
    u32 h1 = h4[0][2*tid+1] + h4[1][2*tid+1] + h4[2][2*tid+1] + h4[3][2*tid+1];
    u32 x = h0 + h1;
#pragma unroll
    for (int off = 1; off < 64; off <<= 1) {
        u32 y = __shfl_down(x, off);
        if (lane + off < 64) x += y;
    }
    if (lane == 0) s_wtot[wave] = x;
    __syncthreads();
    u32 wsuf = 0, tot = 0;
    for (int w2 = 0; w2 < 16; ++w2) { u32 v = s_wtot[w2]; tot += v; if (w2 > wave) wsuf += v; }
    u32 suf0 = x + wsuf, suf1 = suf0 - h0;
    u32 target = (tot < TOPN) ? tot : TOPN;
    if (target > 0) {
        if (suf0 >= target) atomicMax(&s_tf, 2 * tid);
        if (suf1 >= target) atomicMax(&s_tf, 2 * tid + 1);
    }
    __syncthreads();
    int t0 = s_tf;
    if (target > 0) {
        if (2 * tid == t0)     { s_C = suf0; s_above = suf0 - h0; }
        if (2 * tid + 1 == t0) { s_C = suf1; s_above = suf1 - h1; }
    }
    __syncthreads();
    u32 C0 = (target > 0) ? s_C : 0;
    u32 above0 = (target > 0) ? s_above : 0;
    bool useCand = (C0 <= CAPC);

    // ---- phase B: gather bins >= t0 into cbb ----
    for (int base = 0; base < NTOT; base += 1024) {
        int i = base + tid;
        u32 k = (i < NTOT) ? kb[i] : 0u;
        bool pass = (target > 0) && k && ((int)(k >> 21) >= t0);
        u64 mask = __ballot(pass);
        u32 wcnt = (u32)__popcll(mask);
        u32 wbase = 0;
        if (lane == 0 && wcnt) wbase = atomicAdd(&s_cnt, wcnt);
        wbase = __shfl(wbase, 0);
        if (pass) {
            u32 pos = wbase + (u32)__popcll(mask & ((1ull << lane) - 1ull));
            if (pos < CAPC) cbb[pos] = ((u64)k << 32) | (u32)(~i);
        }
    }
    __syncthreads();
    if (tid == 0) s_cnt = 0;

    // ---- phase C: level-2 refine ----
    bool need2 = (target > 0 && C0 > CAP);
    int t1 = 0; u32 C1 = 0, above1 = 0;
    for (int i = tid; i < 4 * 2048; i += 1024) ((u32*)h4)[i] = 0;
    if (tid == 0) s_tf = -1;
    __syncthreads();
    if (need2) {
        if (useCand) {
            for (u32 i = tid; i < C0; i += 1024) {
                u32 k = (u32)(cbb[i] >> 32);
                if ((int)(k >> 21) == t0) atomicAdd(&h4[sub][(k >> 10) & 2047], 1u);
            }
        } else {
            for (int i = tid; i < NTOT; i += 1024) {
                u32 k = kb[i];
                if (k && (int)(k >> 21) == t0) atomicAdd(&h4[sub][(k >> 10) & 2047], 1u);
            }
        }
    }
    __syncthreads();
    {
        u32 g0 = h4[0][2*tid] + h4[1][2*tid] + h4[2][2*tid] + h4[3][2*tid];
        u32 g1 = h4[0][2*tid+1] + h4[1][2*tid+1] + h4[2][2*tid+1] + h4[3][2*tid+1];
        u32 x2 = g0 + g1;
#pragma unroll
        for (int off = 1; off < 64; off <<= 1) {
            u32 y = __shfl_down(x2, off);
            if (lane + off < 64) x2 += y;
        }
        if (lane == 0) s_wtot[wave] = x2;
        __syncthreads();
        u32 ws2 = 0;
        for (int w2 = wave + 1; w2 < 16; ++w2) ws2 += s_wtot[w2];
        u32 sa0 = x2 + ws2, sa1 = sa0 - g0;
        u32 need2c = target - above0;
        if (need2) {
            if (sa0 >= need2c) atomicMax(&s_tf, 2 * tid);
            if (sa1 >= need2c) atomicMax(&s_tf, 2 * tid + 1);
        }
        __syncthreads();
        t1 = s_tf;
        if (need2) {
            if (2 * tid == t1)     { s_C = above0 + sa0; s_above = above0 + sa0 - g0; }
            if (2 * tid + 1 == t1) { s_C = above0 + sa1; s_above = above0 + sa1 - g1; }
        }
        __syncthreads();
        if (need2) { C1 = s_C; above1 = s_above; }
    }

    // ---- phase D: level-3 refine ----
    bool need3 = (need2 && C1 > CAP);
    int t2 = 0;
    __syncthreads();
    for (int i = tid; i < 4 * 2048; i += 1024) ((u32*)h4)[i] = 0;
    if (tid == 0) s_tf = -1;
    __syncthreads();
    if (need3) {
        if (useCand) {
            for (u32 i = tid; i < C0; i += 1024) {
                u32 k = (u32)(cbb[i] >> 32);
                if ((int)(k >> 21) == t0 && (int)((k >> 10) & 2047) == t1)
                    atomicAdd(&h4[sub][k & 1023], 1u);
            }
        } else {
            for (int i = tid; i < NTOT; i += 1024) {
                u32 k = kb[i];
                if (k && (int)(k >> 21) == t0 && (int)((k >> 10) & 2047) == t1)
                    atomicAdd(&h4[sub][k & 1023], 1u);
            }
        }
    }
    __syncthreads();
    {
        u32 g0 = h4[0][2*tid] + h4[1][2*tid] + h4[2][2*tid] + h4[3][2*tid];
        u32 g1 = h4[0][2*tid+1] + h4[1][2*tid+1] + h4[2][2*tid+1] + h4[3][2*tid+1];
        u32 x3 = g0 + g1;
#pragma unroll
        for (int off = 1; off < 64; off <<= 1) {
            u32 y = __shfl_down(x3, off);
            if (lane + off < 64) x3 += y;
        }
        if (lane == 0) s_wtot[wave] = x3;
        __syncthreads();
        u32 ws3 = 0;
        for (int w2 = wave + 1; w2 < 16; ++w2) ws3 += s_wtot[w2];
        u32 sb0 = x3 + ws3, sb1 = sb0 - g0;
        if (need3) {
            u32 need3c = target - above1;
            if (sb0 >= need3c) atomicMax(&s_tf, 2 * tid);
            if (sb1 >= need3c) atomicMax(&s_tf, 2 * tid + 1);
        }
        __syncthreads();
        t2 = s_tf;
    }

    // ---- phase E: final P, compact >=P into cand2 ----
    u32 P;
    if (target == 0) P = 0xFFFFFFFFu;
    else if (!need2) P = (u32)t0 << 21;
    else if (!need3) P = ((u32)t0 << 21) | ((u32)t1 << 10);
    else             P = ((u32)t0 << 21) | ((u32)t1 << 10) | (u32)t2;

    if (useCand) {
        u32 Cr = (C0 + 1023u) & ~1023u;
        for (u32 base = 0; base < Cr; base += 1024) {
            u32 i = base + tid;
            u64 e = 0; bool pass = false;
            if (i < C0 && target > 0) { e = cbb[i]; pass = ((u32)(e >> 32) >= P); }
            u64 mask = __ballot(pass);
            u32 wcnt = (u32)__popcll(mask);
            u32 wbase = 0;
            if (lane == 0 && wcnt) wbase = atomicAdd(&s_cnt, wcnt);
            wbase = __shfl(wbase, 0);
            if (pass) {
                u32 pos = wbase + (u32)__popcll(mask & ((1ull << lane) - 1ull));
                if (pos < CAPC) c2b[pos] = e;
            }
        }
    } else {
        for (int base = 0; base < NTOT; base += 1024) {
            int i = base + tid;
            u32 k = (i < NTOT) ? kb[i] : 0u;
            bool pass = (target > 0) && k && (k >= P);
            u64 mask = __ballot(pass);
            u32 wcnt = (u32)__popcll(mask);
            u32 wbase = 0;
            if (lane == 0 && wcnt) wbase = atomicAdd(&s_cnt, wcnt);
            wbase = __shfl(wbase, 0);
            if (pass) {
                u32 pos = wbase + (u32)__popcll(mask & ((1ull << lane) - 1ull));
                if (pos < CAPC) c2b[pos] = ((u64)k << 32) | (u32)(~i);
            }
        }
    }
    __syncthreads();
    if (tid == 0) {
        u32 M = s_cnt; if (M > CAPC) M = CAPC;
        gcnt[b * 32] = M;
        params[2 * b] = P;
        params[2 * b + 1] = target;
    }
}

// -------------------------------------------------------------------------
// Stage 2c: rank-by-count + scatter; box decode for candidates only.
// Spread over 8 blocks x 16 batches (quadratic work stays parallel).
// -------------------------------------------------------------------------
__global__ __launch_bounds__(256) void rank_kernel(
    const u64* __restrict__ cand2, const u32* __restrict__ gcnt,
    const u32* __restrict__ params,
    const int* __restrict__ clsidx,
    const float* __restrict__ reg0, const float* __restrict__ reg1,
    const float* __restrict__ reg2, const float* __restrict__ reg3,
    const float* __restrict__ reg4,
    float* __restrict__ tscore, float* __restrict__ tcls, float4* __restrict__ tbox)
{
    int b = blockIdx.y;
    int lane = threadIdx.x & 63;
    u32 M = gcnt[b * 32]; if (M > CAPC) M = CAPC;
    u32 target = params[2 * b + 1];
    const u64* cb = cand2 + (size_t)b * CAPC;
    u32 Mr = (M + 63u) & ~63u;

    u32 wbase0 = blockIdx.x * 256 + (threadIdx.x & ~63u);
    for (u32 base = wbase0; base < M; base += 8 * 256) {   // uniform per wave
        u32 i0 = base + lane;
        bool val = (i0 < M);
        u64 e = val ? cb[i0] : ~0ull;
        u32 r = 0;
        for (u32 c0 = 0; c0 < Mr; c0 += 64) {
            u32 j = c0 + lane;
            u64 v = (j < M) ? cb[j] : 0ull;   // 0 is never > any candidate
            u32 vlo = (u32)v, vhi = (u32)(v >> 32);
#pragma unroll
            for (int s = 0; s < 64; ++s) {
                u32 lo = (u32)__builtin_amdgcn_readlane((int)vlo, s);
                u32 hi = (u32)__builtin_amdgcn_readlane((int)vhi, s);
                u64 vj = ((u64)hi << 32) | lo;
                r += (vj > e) ? 1u : 0u;
            }
        }
        if (val && r < target) {
            u32 k = (u32)(e >> 32);
            u32 loc = ~(u32)e;
            const float* rp; float st; u32 li; int wsh;
            if (loc < 16384u)      { li = loc;          wsh = 7; st = 8.f;   rp = reg0 + ((size_t)b*16384 + li)*4; }
            else if (loc < 20480u) { li = loc - 16384u; wsh = 6; st = 16.f;  rp = reg1 + ((size_t)b*4096  + li)*4; }
            else if (loc < 21504u) { li = loc - 20480u; wsh = 5; st = 32.f;  rp = reg2 + ((size_t)b*1024  + li)*4; }
            else if (loc < 21760u) { li = loc - 21504u; wsh = 4; st = 64.f;  rp = reg3 + ((size_t)b*256   + li)*4; }
            else                   { li = loc - 21760u; wsh = 3; st = 128.f; rp = reg4 + ((size_t)b*64    + li)*4; }
            u32 wx = li & ((1u << wsh) - 1u);
            u32 hy = li >> wsh;
            float px = ((float)wx + 0.5f) * st;
            float py = ((float)hy + 0.5f) * st;
            float4 rg = *(const float4*)rp;
            float4 bx;
            bx.x = truncf(px - rg.x); bx.y = truncf(py - rg.y);
            bx.z = truncf(px + rg.z); bx.w = truncf(py + rg.w);
            size_t src = (size_t)b * NTOT + loc;
            size_t o = (size_t)b * TOPN + r;
            tscore[o] = __uint_as_float(k & 0x7FFFFFFFu);
            tcls[o] = (float)clsidx[src];
            tbox[o] = bx;
        }
    }
}

// -------------------------------------------------------------------------
// Stage 3: suppression-bit matrix.  4 rows per 256-thread block (4000
// blocks total -- quadratic work stays machine-wide).
// -------------------------------------------------------------------------
__global__ __launch_bounds__(256) void iou_kernel(
    const float4* __restrict__ tbox, u64* __restrict__ sup)
{
    __shared__ float4 sbox[TOPN];
    int b = blockIdx.y;
    int tid = threadIdx.x, lane = tid & 63, wave = tid >> 6;
    const float4* tb = tbox + (size_t)b * TOPN;
    for (int i = tid; i < TOPN; i += 256) sbox[i] = tb[i];
    __syncthreads();
    int i = blockIdx.x * 4 + wave;
    float4 bi = sbox[i];
    float areai = fmaxf((bi.z - bi.x) * (bi.w - bi.y), 0.0001f);
    u64* row = sup + ((size_t)b * TOPN + i) * 16;
#pragma unroll
    for (int w = 0; w < 16; ++w) {
        int col = w * 64 + lane;
        bool bit = false;
        if (col < TOPN) {
            float4 bj = sbox[col];
            float areaj = fmaxf((bj.z - bj.x) * (bj.w - bj.y), 0.0001f);
            float tlx = fmaxf(bi.x, bj.x), tly = fmaxf(bi.y, bj.y);
            float brx = fminf(bi.z, bj.z), bry = fminf(bi.w, bj.w);
            float ow = fmaxf(brx - tlx, 0.f), oh = fmaxf(bry - tly, 0.f);
            float inter = ow * oh;
            float uni = fmaxf(areai + areaj - inter, 0.0001f);
            bit = (col > i) && (inter / uni >= 0.6f);
        }
        u64 m = __ballot(bit);
        if (lane == 0) row[w] = m;
    }
}

// -------------------------------------------------------------------------
// Stage 4: greedy serial scan + popcount-rank output.
// -------------------------------------------------------------------------
#define CHROWS 128
#define NCHUNK 8

__global__ __launch_bounds__(1024) void finalize_kernel(
    const float* __restrict__ tscore, const float* __restrict__ tcls,
    const float4* __restrict__ tbox, const u64* __restrict__ sup,
    float* __restrict__ out)
{
    __shared__ u64 mat[2][CHROWS * 16];
    __shared__ u32 validsh[TOPN];
    __shared__ u64 removed_sh[16];
    __shared__ u32 wpref[17];
    int b = blockIdx.x, tid = threadIdx.x;
    int wave = tid >> 6, lane = tid & 63;

    for (int i = tid; i < TOPN; i += 1024)
        validsh[i] = (tscore[(size_t)b * TOPN + i] > 0.05f) ? 1u : 0u;

    const u64* supb = sup + (size_t)b * TOPN * 16;
    for (int idx = tid; idx < CHROWS * 16; idx += 1024)
        mat[0][idx] = supb[idx];
    __syncthreads();

    u64 my = 0;
    if (wave == 0) {
#pragma unroll
        for (int w2 = 0; w2 < 16; ++w2) {
            int i = w2 * 64 + lane;
            bool v = (i < TOPN) ? (validsh[i] != 0) : false;
            u64 m = __ballot(v);
            if (lane == w2) my = ~m;
        }
    }

    for (int chunk = 0; chunk < NCHUNK; ++chunk) {
        if (wave > 0 && chunk + 1 < NCHUNK) {
            int nr = (chunk + 1 == NCHUNK - 1) ? (TOPN - (NCHUNK - 1) * CHROWS) : CHROWS;
            const u64* src = supb + (size_t)(chunk + 1) * CHROWS * 16;
            u64* dst = mat[(chunk + 1) & 1];
            for (int idx = tid - 64; idx < nr * 16; idx += 960)
                dst[idx] = src[idx];
        }
        if (wave == 0) {
            int r0 = chunk * CHROWS;
            int rows = (chunk == NCHUNK - 1) ? (TOPN - r0) : CHROWS;
            int lw = lane & 15;
            const u64* M = mat[chunk & 1];
            for (int sub = 0; sub < rows; sub += 64) {
                int w2 = (r0 + sub) >> 6;
                u64 cur = __shfl(my, w2);
                int nsub = rows - sub; if (nsub > 64) nsub = 64;
                const u64* R = M + sub * 16;
                int ngrp = nsub >> 3;
                u64 cme[8], cww[8];
#pragma unroll
                for (int g = 0; g < 8; ++g) { cme[g] = R[g*16 + lw]; cww[g] = R[g*16 + w2]; }
                for (int grp = 0; grp < ngrp; ++grp) {
                    u64 nme[8] = {0,0,0,0,0,0,0,0}, nww[8] = {0,0,0,0,0,0,0,0};
                    if (grp + 1 < ngrp) {
                        const u64* Rn = R + (grp + 1) * 128;
#pragma unroll
                        for (int g = 0; g < 8; ++g) { nme[g] = Rn[g*16 + lw]; nww[g] = Rn[g*16 + w2]; }
                    }
#pragma unroll
                    for (int g = 0; g < 8; ++g) {
                        int u = grp * 8 + g;
                        u64 bit = (cur >> u) & 1ull;
                        u64 act = bit - 1ull;
                        cur |= cww[g] & act;
                        my  |= cme[g] & act;
                    }
#pragma unroll
                    for (int g = 0; g < 8; ++g) { cme[g] = nme[g]; cww[g] = nww[g]; }
                }
            }
        }
        __syncthreads();
    }
    if (wave == 0) {
        if (lane < 16) removed_sh[lane] = my;
        u32 pc = (lane < 16) ? (u32)__popcll(~my) : 0u;
#pragma unroll
        for (int off = 1; off < 16; off <<= 1) {
            u32 y = __shfl_up(pc, off);
            if (lane >= off) pc += y;
        }
        if (lane < 16) wpref[lane + 1] = pc;
        if (lane == 0) wpref[0] = 0;
    }
    __syncthreads();

    float* out_s = out;
    float* out_c = out + NBATCH * MAXOBJ;
    float* out_b = out + 2 * NBATCH * MAXOBJ;
    if (tid < MAXOBJ)     { out_s[b * MAXOBJ + tid] = -1.f; out_c[b * MAXOBJ + tid] = -1.f; }
    if (tid < MAXOBJ * 4) out_b[b * MAXOBJ * 4 + tid] = 0.f;
    __syncthreads();
    if (tid < TOPN) {
        u64 kw = ~removed_sh[tid >> 6];
        if ((kw >> (tid & 63)) & 1ull) {
            int rank = (int)wpref[tid >> 6] + (int)__popcll(kw & ((1ull << (tid & 63)) - 1ull));
            if (rank < MAXOBJ) {
                size_t o = (size_t)b * TOPN + tid;
                out_s[b * MAXOBJ + rank] = tscore[o];
                out_c[b * MAXOBJ + rank] = tcls[o];
                ((float4*)out_b)[b * MAXOBJ + rank] = tbox[o];
            }
        }
    }
}

// -------------------------------------------------------------------------
// Workspace layout (bytes), total 10,812,416 (R6 layout):
//   keys    u32 [16][21824]     @ 0
//   clsidx  i32 [16][21824]     @ 1,396,736
//   cb      u64 [16][8192]      @ 2,793,472
//   cand2   u64 [16][8192]      @ 3,842,048
//   tscore  f32 [16][1000]      @ 8,380,416
//   tcls    f32 [16][1000]      @ 8,444,416
//   tbox    f4  [16][1000]      @ 8,508,416
//   sup     u64 [16][1000][16]  @ 8,764,416
//   gcnt    u32 [16][32] padded @ 9,944,064
//   params  u32 [16][2]         @ 9,946,112
// -------------------------------------------------------------------------
extern "C" void kernel_launch(void* const* d_in, const int* in_sizes, int n_in,
                              void* d_out, int out_size, void* d_ws, size_t ws_size,
                              hipStream_t stream) {
    (void)in_sizes; (void)n_in; (void)out_size; (void)ws_size;
    const float* cls[5]; const float* reg[5]; const float* ctr[5];
    for (int l = 0; l < 5; ++l) {
        cls[l] = (const float*)d_in[4 * l + 0];
        reg[l] = (const float*)d_in[4 * l + 1];
        ctr[l] = (const float*)d_in[4 * l + 2];
    }
    char* w = (char*)d_ws;
    u32*    keys   = (u32*)(w + 0);
    int*    clsidx = (int*)(w + 1396736);
    u64*    cb     = (u64*)(w + 2793472);
    u64*    cand2  = (u64*)(w + 3842048);
    float*  tscore = (float*)(w + 8380416);
    float*  tcls   = (float*)(w + 8444416);
    float4* tbox   = (float4*)(w + 8508416);
    u64*    sup    = (u64*)(w + 8764416);
    u32*    gcnt   = (u32*)(w + 9944064);
    u32*    params = (u32*)(w + 9946112);

    decode_kernel<<<dim3((NTOT + 127) / 128, NBATCH), 256, 0, stream>>>(
        cls[0], cls[1], cls[2], cls[3], cls[4],
        ctr[0], ctr[1], ctr[2], ctr[3], ctr[4],
        keys, clsidx);
    pivot_kernel<<<NBATCH, 1024, 0, stream>>>(keys, cb, cand2, gcnt, params,
                                              tscore, tcls, tbox);
    rank_kernel<<<dim3(8, NBATCH), 256, 0, stream>>>(cand2, gcnt, params, clsidx,
                                                     reg[0], reg[1], reg[2], reg[3], reg[4],
                                                     tscore, tcls, tbox);
    iou_kernel<<<dim3(TOPN / 4, NBATCH), 256, 0, stream>>>(tbox, sup);
    finalize_kernel<<<NBATCH, 1024, 0, stream>>>(tscore, tcls, tbox, sup, (float*)d_out);
}

// Round 10
// 281.821 us; speedup vs baseline: 1.5004x; 1.0072x over previous
//
#include <hip/hip_runtime.h>
#include <stdint.h>

typedef unsigned int u32;
typedef unsigned long long u64;

#define NTOT 21824   // 128*128 + 64*64 + 32*32 + 16*16 + 8*8
#define NBATCH 16
#define TOPN 1000
#define MAXOBJ 100
#define CAP 2048     // refine until candidate count <= CAP
#define CAPC 8192    // candidate buffer capacity per batch

// -------------------------------------------------------------------------
// Stage 1: decode (argmax over 80 classes + score key).  R6-proven form:
// quad-per-location, 4 lanes/location, 64 B contiguous per load.
// -------------------------------------------------------------------------
__global__ __launch_bounds__(256) void decode_kernel(
    const float* __restrict__ cls0, const float* __restrict__ cls1,
    const float* __restrict__ cls2, const float* __restrict__ cls3,
    const float* __restrict__ cls4,
    const float* __restrict__ ctr0, const float* __restrict__ ctr1,
    const float* __restrict__ ctr2, const float* __restrict__ ctr3,
    const float* __restrict__ ctr4,
    u32* __restrict__ keys, int* __restrict__ clsidx)
{
    int tid = threadIdx.x;
    int g = tid >> 2, j = tid & 3;          // location-in-block, quad sub
    int loc = blockIdx.x * 64 + g;          // level-uniform per block
    int b = blockIdx.y;
    if (loc >= NTOT) return;
    const float *cp, *tp;
    if (loc < 16384)      { size_t o = (size_t)b*16384 + loc;          cp = cls0 + o*80; tp = ctr0 + o; }
    else if (loc < 20480) { size_t o = (size_t)b*4096  + (loc-16384);  cp = cls1 + o*80; tp = ctr1 + o; }
    else if (loc < 21504) { size_t o = (size_t)b*1024  + (loc-20480);  cp = cls2 + o*80; tp = ctr2 + o; }
    else if (loc < 21760) { size_t o = (size_t)b*256   + (loc-21504);  cp = cls3 + o*80; tp = ctr3 + o; }
    else                  { size_t o = (size_t)b*64    + (loc-21760);  cp = cls4 + o*80; tp = ctr4 + o; }

    const float4* c4 = (const float4*)cp;
    float maxv = -1.0f; int arg = 0;
#pragma unroll
    for (int q = 0; q < 5; ++q) {
        float4 v = c4[j + 4*q];
        int ch = 16*q + 4*j;
        if (v.x > maxv) { maxv = v.x; arg = ch;     }
        if (v.y > maxv) { maxv = v.y; arg = ch + 1; }
        if (v.z > maxv) { maxv = v.z; arg = ch + 2; }
        if (v.w > maxv) { maxv = v.w; arg = ch + 3; }
    }
    // quad reduction, exact first-max tie-break (lowest channel wins)
#pragma unroll
    for (int d = 1; d <= 2; d <<= 1) {
        float ov = __shfl_xor(maxv, d);
        int   oa = __shfl_xor(arg, d);
        if (ov > maxv || (ov == maxv && oa < arg)) { maxv = ov; arg = oa; }
    }
    if (j == 0) {
        float score = sqrtf(maxv * (*tp));   // correctly-rounded fp32 sqrt
        u32 key = (score > 0.05f) ? (__float_as_uint(score) | 0x80000000u) : 0u;
        size_t o = (size_t)b * NTOT + loc;
        keys[o] = key;
        clsidx[o] = arg;
    }
}

// -------------------------------------------------------------------------
// Stage 2: pivot + gather + compact, one block per batch (R6-proven).
// Phase C/D bodies now skipped entirely (uniform branch) when not needed.
// -------------------------------------------------------------------------
__global__ __launch_bounds__(1024) void pivot_kernel(
    const u32* __restrict__ keys,
    u64* __restrict__ cb, u64* __restrict__ cand2,
    u32* __restrict__ gcnt, u32* __restrict__ params,
    float* __restrict__ tscore, float* __restrict__ tcls, float4* __restrict__ tbox)
{
    __shared__ u32 h4[4][2048];     // 32 KB
    __shared__ u32 s_wtot[16];
    __shared__ int s_tf;
    __shared__ u32 s_C, s_above, s_cnt;
    int b = blockIdx.x, tid = threadIdx.x;
    int lane = tid & 63, wave = tid >> 6, sub = wave & 3;
    const u32* kb = keys + (size_t)b * NTOT;
    u64* cbb = cb + (size_t)b * CAPC;
    u64* c2b = cand2 + (size_t)b * CAPC;

    for (int i = tid; i < TOPN; i += 1024) {
        size_t o = (size_t)b * TOPN + i;
        tscore[o] = -1.0f; tcls[o] = -1.0f;
        tbox[o] = make_float4(0.f, 0.f, 0.f, 0.f);
    }

    // ---- phase A: 11-bit histogram from keys ----
    for (int i = tid; i < 4 * 2048; i += 1024) ((u32*)h4)[i] = 0;
    if (tid == 0) { s_tf = -1; s_cnt = 0; }
    __syncthreads();
    for (int i = tid; i < NTOT; i += 1024) {
        u32 k = kb[i];
        if (k) atomicAdd(&h4[sub][k >> 21], 1u);
    }
    __syncthreads();
    u32 h0 = h4[0][2*tid] + h4[1][2*tid] + h4[2][2*tid] + h4[3][2*tid];
    u32 h1 = h4[0][2*tid+1] + h4[1][2*tid+1] + h4[2][2*tid+1] + h4[3][2*tid+1];
    u32 x = h0 + h1;
#pragma unroll
    for (int off = 1; off < 64; off <<= 1) {
        u32 y = __shfl_down(x, off);
        if (lane + off < 64) x += y;
    }
    if (lane == 0) s_wtot[wave] = x;
    __syncthreads();
    u32 wsuf = 0, tot = 0;
    for (int w2 = 0; w2 < 16; ++w2) { u32 v = s_wtot[w2]; tot += v; if (w2 > wave) wsuf += v; }
    u32 suf0 = x + wsuf, suf1 = suf0 - h0;
    u32 target = (tot < TOPN) ? tot : TOPN;
    if (target > 0) {
        if (suf0 >= target) atomicMax(&s_tf, 2 * tid);
        if (suf1 >= target) atomicMax(&s_tf, 2 * tid + 1);
    }
    __syncthreads();
    int t0 = s_tf;
    if (target > 0) {
        if (2 * tid == t0)     { s_C = suf0; s_above = suf0 - h0; }
        if (2 * tid + 1 == t0) { s_C = suf1; s_above = suf1 - h1; }
    }
    __syncthreads();
    u32 C0 = (target > 0) ? s_C : 0;
    u32 above0 = (target > 0) ? s_above : 0;
    bool useCand = (C0 <= CAPC);

    // ---- phase B: gather bins >= t0 into cbb ----
    for (int base = 0; base < NTOT; base += 1024) {
        int i = base + tid;
        u32 k = (i < NTOT) ? kb[i] : 0u;
        bool pass = (target > 0) && k && ((int)(k >> 21) >= t0);
        u64 mask = __ballot(pass);
        u32 wcnt = (u32)__popcll(mask);
        u32 wbase = 0;
        if (lane == 0 && wcnt) wbase = atomicAdd(&s_cnt, wcnt);
        wbase = __shfl(wbase, 0);
        if (pass) {
            u32 pos = wbase + (u32)__popcll(mask & ((1ull << lane) - 1ull));
            if (pos < CAPC) cbb[pos] = ((u64)k << 32) | (u32)(~i);
        }
    }
    __syncthreads();
    if (tid == 0) s_cnt = 0;

    // ---- phase C: level-2 refine (skipped uniformly when not needed) ----
    bool need2 = (target > 0 && C0 > CAP);
    int t1 = 0; u32 C1 = 0, above1 = 0;
    if (need2) {
        for (int i = tid; i < 4 * 2048; i += 1024) ((u32*)h4)[i] = 0;
        if (tid == 0) s_tf = -1;
        __syncthreads();
        if (useCand) {
            for (u32 i = tid; i < C0; i += 1024) {
                u32 k = (u32)(cbb[i] >> 32);
                if ((int)(k >> 21) == t0) atomicAdd(&h4[sub][(k >> 10) & 2047], 1u);
            }
        } else {
            for (int i = tid; i < NTOT; i += 1024) {
                u32 k = kb[i];
                if (k && (int)(k >> 21) == t0) atomicAdd(&h4[sub][(k >> 10) & 2047], 1u);
            }
        }
        __syncthreads();
        u32 g0 = h4[0][2*tid] + h4[1][2*tid] + h4[2][2*tid] + h4[3][2*tid];
        u32 g1 = h4[0][2*tid+1] + h4[1][2*tid+1] + h4[2][2*tid+1] + h4[3][2*tid+1];
        u32 x2 = g0 + g1;
#pragma unroll
        for (int off = 1; off < 64; off <<= 1) {
            u32 y = __shfl_down(x2, off);
            if (lane + off < 64) x2 += y;
        }
        if (lane == 0) s_wtot[wave] = x2;
        __syncthreads();
        u32 ws2 = 0;
        for (int w2 = wave + 1; w2 < 16; ++w2) ws2 += s_wtot[w2];
        u32 sa0 = x2 + ws2, sa1 = sa0 - g0;
        u32 need2c = target - above0;
        if (sa0 >= need2c) atomicMax(&s_tf, 2 * tid);
        if (sa1 >= need2c) atomicMax(&s_tf, 2 * tid + 1);
        __syncthreads();
        t1 = s_tf;
        if (2 * tid == t1)     { s_C = above0 + sa0; s_above = above0 + sa0 - g0; }
        if (2 * tid + 1 == t1) { s_C = above0 + sa1; s_above = above0 + sa1 - g1; }
        __syncthreads();
        C1 = s_C; above1 = s_above;
    }

    // ---- phase D: level-3 refine (skipped uniformly when not needed) ----
    bool need3 = (need2 && C1 > CAP);
    int t2 = 0;
    if (need3) {
        __syncthreads();
        for (int i = tid; i < 4 * 2048; i += 1024) ((u32*)h4)[i] = 0;
        if (tid == 0) s_tf = -1;
        __syncthreads();
        if (useCand) {
            for (u32 i = tid; i < C0; i += 1024) {
                u32 k = (u32)(cbb[i] >> 32);
                if ((int)(k >> 21) == t0 && (int)((k >> 10) & 2047) == t1)
                    atomicAdd(&h4[sub][k & 1023], 1u);
            }
        } else {
            for (int i = tid; i < NTOT; i += 1024) {
                u32 k = kb[i];
                if (k && (int)(k >> 21) == t0 && (int)((k >> 10) & 2047) == t1)
                    atomicAdd(&h4[sub][k & 1023], 1u);
            }
        }
        __syncthreads();
        u32 g0 = h4[0][2*tid] + h4[1][2*tid] + h4[2][2*tid] + h4[3][2*tid];
        u32 g1 = h4[0][2*tid+1] + h4[1][2*tid+1] + h4[2][2*tid+1] + h4[3][2*tid+1];
        u32 x3 = g0 + g1;
#pragma unroll
        for (int off = 1; off < 64; off <<= 1) {
            u32 y = __shfl_down(x3, off);
            if (lane + off < 64) x3 += y;
        }
        if (lane == 0) s_wtot[wave] = x3;
        __syncthreads();
        u32 ws3 = 0;
        for (int w2 = wave + 1; w2 < 16; ++w2) ws3 += s_wtot[w2];
        u32 sb0 = x3 + ws3, sb1 = sb0 - g0;
        u32 need3c = target - above1;
        if (sb0 >= need3c) atomicMax(&s_tf, 2 * tid);
        if (sb1 >= need3c) atomicMax(&s_tf, 2 * tid + 1);
        __syncthreads();
        t2 = s_tf;
    }

    // ---- phase E: final P, compact >=P into cand2 ----
    u32 P;
    if (target == 0) P = 0xFFFFFFFFu;
    else if (!need2) P = (u32)t0 << 21;
    else if (!need3) P = ((u32)t0 << 21) | ((u32)t1 << 10);
    else             P = ((u32)t0 << 21) | ((u32)t1 << 10) | (u32)t2;

    __syncthreads();
    if (useCand) {
        u32 Cr = (C0 + 1023u) & ~1023u;
        for (u32 base = 0; base < Cr; base += 1024) {
            u32 i = base + tid;
            u64 e = 0; bool pass = false;
            if (i < C0 && target > 0) { e = cbb[i]; pass = ((u32)(e >> 32) >= P); }
            u64 mask = __ballot(pass);
            u32 wcnt = (u32)__popcll(mask);
            u32 wbase = 0;
            if (lane == 0 && wcnt) wbase = atomicAdd(&s_cnt, wcnt);
            wbase = __shfl(wbase, 0);
            if (pass) {
                u32 pos = wbase + (u32)__popcll(mask & ((1ull << lane) - 1ull));
                if (pos < CAPC) c2b[pos] = e;
            }
        }
    } else {
        for (int base = 0; base < NTOT; base += 1024) {
            int i = base + tid;
            u32 k = (i < NTOT) ? kb[i] : 0u;
            bool pass = (target > 0) && k && (k >= P);
            u64 mask = __ballot(pass);
            u32 wcnt = (u32)__popcll(mask);
            u32 wbase = 0;
            if (lane == 0 && wcnt) wbase = atomicAdd(&s_cnt, wcnt);
            wbase = __shfl(wbase, 0);
            if (pass) {
                u32 pos = wbase + (u32)__popcll(mask & ((1ull << lane) - 1ull));
                if (pos < CAPC) c2b[pos] = ((u64)k << 32) | (u32)(~i);
            }
        }
    }
    __syncthreads();
    if (tid == 0) {
        u32 M = s_cnt; if (M > CAPC) M = CAPC;
        gcnt[b * 32] = M;
        params[2 * b] = P;
        params[2 * b + 1] = target;
    }
}

// -------------------------------------------------------------------------
// Stage 2c: rank-by-count + scatter; box decode for candidates only.
// -------------------------------------------------------------------------
__global__ __launch_bounds__(256) void rank_kernel(
    const u64* __restrict__ cand2, const u32* __restrict__ gcnt,
    const u32* __restrict__ params,
    const int* __restrict__ clsidx,
    const float* __restrict__ reg0, const float* __restrict__ reg1,
    const float* __restrict__ reg2, const float* __restrict__ reg3,
    const float* __restrict__ reg4,
    float* __restrict__ tscore, float* __restrict__ tcls, float4* __restrict__ tbox)
{
    int b = blockIdx.y;
    int lane = threadIdx.x & 63;
    u32 M = gcnt[b * 32]; if (M > CAPC) M = CAPC;
    u32 target = params[2 * b + 1];
    const u64* cb = cand2 + (size_t)b * CAPC;
    u32 Mr = (M + 63u) & ~63u;

    u32 wbase0 = blockIdx.x * 256 + (threadIdx.x & ~63u);
    for (u32 base = wbase0; base < M; base += 8 * 256) {   // uniform per wave
        u32 i0 = base + lane;
        bool val = (i0 < M);
        u64 e = val ? cb[i0] : ~0ull;
        u32 r = 0;
        for (u32 c0 = 0; c0 < Mr; c0 += 64) {
            u32 j = c0 + lane;
            u64 v = (j < M) ? cb[j] : 0ull;   // 0 is never > any candidate
            u32 vlo = (u32)v, vhi = (u32)(v >> 32);
#pragma unroll
            for (int s = 0; s < 64; ++s) {
                u32 lo = (u32)__builtin_amdgcn_readlane((int)vlo, s);
                u32 hi = (u32)__builtin_amdgcn_readlane((int)vhi, s);
                u64 vj = ((u64)hi << 32) | lo;
                r += (vj > e) ? 1u : 0u;
            }
        }
        if (val && r < target) {
            u32 k = (u32)(e >> 32);
            u32 loc = ~(u32)e;
            const float* rp; float st; u32 li; int wsh;
            if (loc < 16384u)      { li = loc;          wsh = 7; st = 8.f;   rp = reg0 + ((size_t)b*16384 + li)*4; }
            else if (loc < 20480u) { li = loc - 16384u; wsh = 6; st = 16.f;  rp = reg1 + ((size_t)b*4096  + li)*4; }
            else if (loc < 21504u) { li = loc - 20480u; wsh = 5; st = 32.f;  rp = reg2 + ((size_t)b*1024  + li)*4; }
            else if (loc < 21760u) { li = loc - 21504u; wsh = 4; st = 64.f;  rp = reg3 + ((size_t)b*256   + li)*4; }
            else                   { li = loc - 21760u; wsh = 3; st = 128.f; rp = reg4 + ((size_t)b*64    + li)*4; }
            u32 wx = li & ((1u << wsh) - 1u);
            u32 hy = li >> wsh;
            float px = ((float)wx + 0.5f) * st;
            float py = ((float)hy + 0.5f) * st;
            float4 rg = *(const float4*)rp;
            float4 bx;
            bx.x = truncf(px - rg.x); bx.y = truncf(py - rg.y);
            bx.z = truncf(px + rg.z); bx.w = truncf(py + rg.w);
            size_t src = (size_t)b * NTOT + loc;
            size_t o = (size_t)b * TOPN + r;
            tscore[o] = __uint_as_float(k & 0x7FFFFFFFu);
            tcls[o] = (float)clsidx[src];
            tbox[o] = bx;
        }
    }
}

// -------------------------------------------------------------------------
// Stage 3: suppression-bit matrix, upper-triangle words only.
// bit(i,j)=0 for j<=i, so words w < i>>6 are structurally zero: neither
// computed nor written (finalize zero-fills them).  ~45% less work+traffic.
// -------------------------------------------------------------------------
__global__ __launch_bounds__(256) void iou_kernel(
    const float4* __restrict__ tbox, u64* __restrict__ sup)
{
    __shared__ float4 sbox[TOPN];
    int b = blockIdx.y;
    int tid = threadIdx.x, lane = tid & 63, wave = tid >> 6;
    const float4* tb = tbox + (size_t)b * TOPN;
    for (int i = tid; i < TOPN; i += 256) sbox[i] = tb[i];
    __syncthreads();
    int i = blockIdx.x * 4 + wave;
    float4 bi = sbox[i];
    float areai = fmaxf((bi.z - bi.x) * (bi.w - bi.y), 0.0001f);
    u64* row = sup + ((size_t)b * TOPN + i) * 16;
    int wstart = i >> 6;                     // uniform per wave
    for (int w = wstart; w < 16; ++w) {
        int col = w * 64 + lane;
        bool bit = false;
        if (col < TOPN) {
            float4 bj = sbox[col];
            float areaj = fmaxf((bj.z - bj.x) * (bj.w - bj.y), 0.0001f);
            float tlx = fmaxf(bi.x, bj.x), tly = fmaxf(bi.y, bj.y);
            float brx = fminf(bi.z, bj.z), bry = fminf(bi.w, bj.w);
            float ow = fmaxf(brx - tlx, 0.f), oh = fmaxf(bry - tly, 0.f);
            float inter = ow * oh;
            float uni = fmaxf(areai + areaj - inter, 0.0001f);
            bit = (col > i) && (inter / uni >= 0.6f);
        }
        u64 m = __ballot(bit);
        if (lane == 0) row[w] = m;
    }
}

// -------------------------------------------------------------------------
// Stage 4: greedy serial scan + popcount-rank output.  Staging zero-fills
// the never-written lower-triangle words.
// -------------------------------------------------------------------------
#define CHROWS 128
#define NCHUNK 8

__global__ __launch_bounds__(1024) void finalize_kernel(
    const float* __restrict__ tscore, const float* __restrict__ tcls,
    const float4* __restrict__ tbox, const u64* __restrict__ sup,
    float* __restrict__ out)
{
    __shared__ u64 mat[2][CHROWS * 16];
    __shared__ u32 validsh[TOPN];
    __shared__ u64 removed_sh[16];
    __shared__ u32 wpref[17];
    int b = blockIdx.x, tid = threadIdx.x;
    int wave = tid >> 6, lane = tid & 63;

    for (int i = tid; i < TOPN; i += 1024)
        validsh[i] = (tscore[(size_t)b * TOPN + i] > 0.05f) ? 1u : 0u;

    const u64* supb = sup + (size_t)b * TOPN * 16;
    for (int idx = tid; idx < CHROWS * 16; idx += 1024) {
        int r = idx >> 4, w2 = idx & 15;     // chunk 0: row == r
        mat[0][idx] = (w2 < (r >> 6)) ? 0ull : supb[idx];
    }
    __syncthreads();

    u64 my = 0;
    if (wave == 0) {
#pragma unroll
        for (int w2 = 0; w2 < 16; ++w2) {
            int i = w2 * 64 + lane;
            bool v = (i < TOPN) ? (validsh[i] != 0) : false;
            u64 m = __ballot(v);
            if (lane == w2) my = ~m;
        }
    }

    for (int chunk = 0; chunk < NCHUNK; ++chunk) {
        if (wave > 0 && chunk + 1 < NCHUNK) {
            int r0n = (chunk + 1) * CHROWS;
            int nr = (chunk + 1 == NCHUNK - 1) ? (TOPN - (NCHUNK - 1) * CHROWS) : CHROWS;
            const u64* src = supb + (size_t)r0n * 16;
            u64* dst = mat[(chunk + 1) & 1];
            for (int idx = tid - 64; idx < nr * 16; idx += 960) {
                int r = idx >> 4, w2 = idx & 15;
                dst[idx] = (w2 < ((r0n + r) >> 6)) ? 0ull : src[idx];
            }
        }
        if (wave == 0) {
            int r0 = chunk * CHROWS;
            int rows = (chunk == NCHUNK - 1) ? (TOPN - r0) : CHROWS;
            int lw = lane & 15;
            const u64* M = mat[chunk & 1];
            for (int sub = 0; sub < rows; sub += 64) {
                int w2 = (r0 + sub) >> 6;
                u64 cur = __shfl(my, w2);
                int nsub = rows - sub; if (nsub > 64) nsub = 64;
                const u64* R = M + sub * 16;
                int ngrp = nsub >> 3;
                u64 cme[8], cww[8];
#pragma unroll
                for (int g = 0; g < 8; ++g) { cme[g] = R[g*16 + lw]; cww[g] = R[g*16 + w2]; }
                for (int grp = 0; grp < ngrp; ++grp) {
                    u64 nme[8] = {0,0,0,0,0,0,0,0}, nww[8] = {0,0,0,0,0,0,0,0};
                    if (grp + 1 < ngrp) {
                        const u64* Rn = R + (grp + 1) * 128;
#pragma unroll
                        for (int g = 0; g < 8; ++g) { nme[g] = Rn[g*16 + lw]; nww[g] = Rn[g*16 + w2]; }
                    }
#pragma unroll
                    for (int g = 0; g < 8; ++g) {
                        int u = grp * 8 + g;
                        u64 bit = (cur >> u) & 1ull;
                        u64 act = bit - 1ull;
                        cur |= cww[g] & act;
                        my  |= cme[g] & act;
                    }
#pragma unroll
                    for (int g = 0; g < 8; ++g) { cme[g] = nme[g]; cww[g] = nww[g]; }
                }
            }
        }
        __syncthreads();
    }
    if (wave == 0) {
        if (lane < 16) removed_sh[lane] = my;
        u32 pc = (lane < 16) ? (u32)__popcll(~my) : 0u;
#pragma unroll
        for (int off = 1; off < 16; off <<= 1) {
            u32 y = __shfl_up(pc, off);
            if (lane >= off) pc += y;
        }
        if (lane < 16) wpref[lane + 1] = pc;
        if (lane == 0) wpref[0] = 0;
    }
    __syncthreads();

    float* out_s = out;
    float* out_c = out + NBATCH * MAXOBJ;
    float* out_b = out + 2 * NBATCH * MAXOBJ;
    if (tid < MAXOBJ)     { out_s[b * MAXOBJ + tid] = -1.f; out_c[b * MAXOBJ + tid] = -1.f; }
    if (tid < MAXOBJ * 4) out_b[b * MAXOBJ * 4 + tid] = 0.f;
    __syncthreads();
    if (tid < TOPN) {
        u64 kw = ~removed_sh[tid >> 6];
        if ((kw >> (tid & 63)) & 1ull) {
            int rank = (int)wpref[tid >> 6] + (int)__popcll(kw & ((1ull << (tid & 63)) - 1ull));
            if (rank < MAXOBJ) {
                size_t o = (size_t)b * TOPN + tid;
                out_s[b * MAXOBJ + rank] = tscore[o];
                out_c[b * MAXOBJ + rank] = tcls[o];
                ((float4*)out_b)[b * MAXOBJ + rank] = tbox[o];
            }
        }
    }
}

// -------------------------------------------------------------------------
// Workspace layout (bytes), total 10,812,416 (R6 layout):
//   keys    u32 [16][21824]     @ 0
//   clsidx  i32 [16][21824]     @ 1,396,736
//   cb      u64 [16][8192]      @ 2,793,472
//   cand2   u64 [16][8192]      @ 3,842,048
//   tscore  f32 [16][1000]      @ 8,380,416
//   tcls    f32 [16][1000]      @ 8,444,416
//   tbox    f4  [16][1000]      @ 8,508,416
//   sup     u64 [16][1000][16]  @ 8,764,416  (upper-triangle words only)
//   gcnt    u32 [16][32] padded @ 9,944,064
//   params  u32 [16][2]         @ 9,946,112
// -------------------------------------------------------------------------
extern "C" void kernel_launch(void* const* d_in, const int* in_sizes, int n_in,
                              void* d_out, int out_size, void* d_ws, size_t ws_size,
                              hipStream_t stream) {
    (void)in_sizes; (void)n_in; (void)out_size; (void)ws_size;
    const float* cls[5]; const float* reg[5]; const float* ctr[5];
    for (int l = 0; l < 5; ++l) {
        cls[l] = (const float*)d_in[4 * l + 0];
        reg[l] = (const float*)d_in[4 * l + 1];
        ctr[l] = (const float*)d_in[4 * l + 2];
    }
    char* w = (char*)d_ws;
    u32*    keys   = (u32*)(w + 0);
    int*    clsidx = (int*)(w + 1396736);
    u64*    cb     = (u64*)(w + 2793472);
    u64*    cand2  = (u64*)(w + 3842048);
    float*  tscore = (float*)(w + 8380416);
    float*  tcls   = (float*)(w + 8444416);
    float4* tbox   = (float4*)(w + 8508416);
    u64*    sup    = (u64*)(w + 8764416);
    u32*    gcnt   = (u32*)(w + 9944064);
    u32*    params = (u32*)(w + 9946112);

    decode_kernel<<<dim3((NTOT + 63) / 64, NBATCH), 256, 0, stream>>>(
        cls[0], cls[1], cls[2], cls[3], cls[4],
        ctr[0], ctr[1], ctr[2], ctr[3], ctr[4],
        keys, clsidx);
    pivot_kernel<<<NBATCH, 1024, 0, stream>>>(keys, cb, cand2, gcnt, params,
                                              tscore, tcls, tbox);
    rank_kernel<<<dim3(8, NBATCH), 256, 0, stream>>>(cand2, gcnt, params, clsidx,
                                                     reg[0], reg[1], reg[2], reg[3], reg[4],
                                                     tscore, tcls, tbox);
    iou_kernel<<<dim3(TOPN / 4, NBATCH), 256, 0, stream>>>(tbox, sup);
    finalize_kernel<<<NBATCH, 1024, 0, stream>>>(tscore, tcls, tbox, sup, (float*)d_out);
}